// Round 9
// baseline (78.297 us; speedup 1.0000x reference)
//
#include <hip/hip_runtime.h>
#include <math.h>

// Problem constants (match reference)
#define Bdim 8
#define Lq   256
#define Hd   128

static constexpr float kNEG = -4294967295.0f;           // -(2^32)+1 as f32
static constexpr float kScale = 0.17677669529663687f;   // 1/sqrt(32)
static constexpr float kUni = 0.00390625f;              // 1/256 (exact)

// ---------------------------------------------------------------------------
// prep: blocks 0-11 transpose Wq/Wk/Wv (64x64 LDS tiles, coalesced both ways);
//       block 12 normalizes the bool time_mask (u8 vs i32 auto-detect).
// ---------------------------------------------------------------------------
__global__ __launch_bounds__(256) void prep_kernel(
    const float* __restrict__ Wq, const float* __restrict__ Wk,
    const float* __restrict__ Wv, const unsigned char* __restrict__ raw,
    float* __restrict__ Wt, int* __restrict__ outmask)
{
    const int blk = blockIdx.x;
    if (blk < 12) {
        __shared__ float tile[64][65];
        const int mi = blk >> 2;
        const float* W = (mi == 0) ? Wq : (mi == 1) ? Wk : Wv;
        float* WT = Wt + mi * (Hd * Hd);
        const int ti = blk & 3;
        const int r0 = (ti >> 1) * 64, c0 = (ti & 1) * 64;
        #pragma unroll
        for (int k = 0; k < 16; ++k) {
            const int e = threadIdx.x + k * 256;
            const int r = e >> 6, c = e & 63;
            tile[r][c] = W[(r0 + r) * Hd + (c0 + c)];
        }
        __syncthreads();
        #pragma unroll
        for (int k = 0; k < 16; ++k) {
            const int e = threadIdx.x + k * 256;
            const int r = e >> 6, c = e & 63;
            WT[(c0 + r) * Hd + (r0 + c)] = tile[c][r];
        }
    } else {
        __shared__ int cnt;
        if (threadIdx.x == 0) cnt = 0;
        __syncthreads();
        const int n = Bdim * Lq;
        for (int i = threadIdx.x; i < n; i += 256)
            if ((i & 3) && raw[i]) atomicAdd(&cnt, 1);
        __syncthreads();
        const bool is_u8 = (cnt > 0);
        const int* raw32 = (const int*)raw;
        for (int i = threadIdx.x; i < n; i += 256) {
            const int v = is_u8 ? (int)raw[i] : raw32[i];
            outmask[i] = (v != 0) ? 1 : 0;
        }
    }
}

// ---------------------------------------------------------------------------
// Projections (fused abs_pos adds), W pre-transposed so loads are coalesced.
// 512 threads (8 waves/block): o = tid&127, rh = tid>>7, 2 rows/thread.
// ---------------------------------------------------------------------------
__global__ __launch_bounds__(512) void proj_kernel(
    const float* __restrict__ queries, const float* __restrict__ keys,
    const float* __restrict__ absK, const float* __restrict__ absV,
    const float* __restrict__ Wt,
    const float* __restrict__ bq, const float* __restrict__ bk,
    const float* __restrict__ bv,
    float* __restrict__ Qb, float* __restrict__ Kb, float* __restrict__ Vb)
{
    constexpr int R = 8;
    __shared__ float xq[R][Hd];
    __shared__ float xk[R][Hd];
    const int row0 = blockIdx.x * R;
    const int tid = threadIdx.x;
    #pragma unroll
    for (int k = 0; k < 2; ++k) {
        const int e = tid + k * 512;
        const int r = e >> 7, c = e & 127;
        xq[r][c] = queries[(row0 + r) * Hd + c];
        xk[r][c] = keys[(row0 + r) * Hd + c];
    }
    __syncthreads();

    const int o = tid & 127, rh = tid >> 7;
    const int r0 = rh * 2, r1 = rh * 2 + 1;
    const float* __restrict__ Wtq = Wt;
    const float* __restrict__ Wtk = Wt + Hd * Hd;
    const float* __restrict__ Wtv = Wt + 2 * Hd * Hd;

    float qa0 = bq[o], qa1 = qa0;
    float ka0 = bk[o] + absK[(row0 + r0) * Hd + o];
    float ka1 = bk[o] + absK[(row0 + r1) * Hd + o];
    float va0 = bv[o] + absV[(row0 + r0) * Hd + o];
    float va1 = bv[o] + absV[(row0 + r1) * Hd + o];

    #pragma unroll 4
    for (int i = 0; i < Hd; ++i) {
        const float wq = Wtq[i * Hd + o];
        const float wk = Wtk[i * Hd + o];
        const float wv = Wtv[i * Hd + o];
        const float x0 = xq[r0][i], x1 = xq[r1][i];
        const float y0 = xk[r0][i], y1 = xk[r1][i];
        qa0 += x0 * wq; qa1 += x1 * wq;
        ka0 += y0 * wk; ka1 += y1 * wk;
        va0 += y0 * wv; va1 += y1 * wv;
    }
    Qb[(row0 + r0) * Hd + o] = qa0;  Qb[(row0 + r1) * Hd + o] = qa1;
    Kb[(row0 + r0) * Hd + o] = ka0;  Kb[(row0 + r1) * Hd + o] = ka1;
    Vb[(row0 + r0) * Hd + o] = va0;  Vb[(row0 + r1) * Hd + o] = va1;
}

// ---------------------------------------------------------------------------
// Fused attention v6: 1024 blocks = (b:8) x (pair p:128). Block handles BOTH
// complementary rows l0=p, l1=255-p (constant work per block) and ALL 4 heads
// (each wave reads FULL 512B rows -> linear DRAM streams, no 128B quarters).
// Waves split the m-tiles: wave w does tiles t = w, w+4, w+8, w+12.
// Lane map: cg = lane&15 (ch = cg*8, all 128 channels), mo = lane>>4 (4 rows
// per inst-group); per-head score = quad (lane bits 0,1) shuffle reduce.
// Scores in LDS sc[l][head][m] (padded 264: conflict-free); per-head softmax
// by wave w = head w (guarded reads, exact-0 writeback beyond l); output
// partials reduced across waves via op[] LDS. Masked rows: exact uniform
// 1/256 path. 3 barriers. __launch_bounds__(256,4): 4 uniform blocks/CU.
// ---------------------------------------------------------------------------
__global__ __launch_bounds__(256, 4) void attn_kernel(
    const float* __restrict__ Qb, const float* __restrict__ Kb,
    const float* __restrict__ Vb,
    const float* __restrict__ tK, const float* __restrict__ tV,
    const int* __restrict__ tmask, float* __restrict__ out)
{
    const int bid = blockIdx.x;
    const int b = bid & 7;
    const int p = bid >> 3;                 // 0..127
    const int l0 = p, l1 = 255 - p;

    const int tid = threadIdx.x;
    const int w = tid >> 6;                 // wave 0..3
    const int lane = tid & 63;
    const int cg = lane & 15;               // channel group: ch = cg*8
    const int mo = lane >> 4;               // 0..3: row within sub-group
    const int hq = cg >> 2;                 // head owning this lane's channels

    __shared__ float sc[2][4][264];         // [l][head][m], padded
    __shared__ float op[4][2][128];         // [wave][l][ch] output partials

    const size_t row0 = ((size_t)b * Lq + l0) * Hd;
    const size_t row1 = ((size_t)b * Lq + l1) * Hd;

    // Q for this lane's 8 channels, both rows, pre-scaled by 1/sqrt(D)
    float4 q00 = *(const float4*)(Qb + row0 + cg * 8);
    float4 q01 = *(const float4*)(Qb + row0 + cg * 8 + 4);
    float4 q10 = *(const float4*)(Qb + row1 + cg * 8);
    float4 q11 = *(const float4*)(Qb + row1 + cg * 8 + 4);
    q00.x*=kScale; q00.y*=kScale; q00.z*=kScale; q00.w*=kScale;
    q01.x*=kScale; q01.y*=kScale; q01.z*=kScale; q01.w*=kScale;
    q10.x*=kScale; q10.y*=kScale; q10.z*=kScale; q10.w*=kScale;
    q11.x*=kScale; q11.y*=kScale; q11.z*=kScale; q11.w*=kScale;

    const bool mk0 = (tmask[b * Lq + l0] != 0);
    const bool mk1 = (tmask[b * Lq + l1] != 0);
    const int ntc0 = (l0 >> 4) + 1, ntc1 = (l1 >> 4) + 1;
    const int n10 = mk0 ? 0 : ntc0, n11 = mk1 ? 0 : ntc1;
    const int NT1 = (n10 > n11) ? n10 : n11;
    const int n20 = mk0 ? 16 : ntc0, n21 = mk1 ? 16 : ntc1;
    const int NT2 = (n20 > n21) ? n20 : n21;

    // per-lane base pointers at row mo, channel cg*8 (full-row linear reads)
    const float* kp  = Kb + (size_t)b * Lq * Hd + (size_t)mo * Hd + cg * 8;
    const float* vp  = Vb + (size_t)b * Lq * Hd + (size_t)mo * Hd + cg * 8;
    const float* t0p = tK + row0 * Lq + (size_t)mo * Hd + cg * 8;
    const float* t1p = tK + row1 * Lq + (size_t)mo * Hd + cg * 8;
    const float* u0p = tV + row0 * Lq + (size_t)mo * Hd + cg * 8;
    const float* u1p = tV + row1 * Lq + (size_t)mo * Hd + cg * 8;

    // ---- phase 1: scores -> LDS (wave w does tiles w, w+4, w+8, w+12) ----
    for (int k = 0; k < 4; ++k) {
        const int t = w + k * 4;
        if (t >= NT1) break;
        #pragma unroll
        for (int sub = 0; sub < 4; ++sub) {
            const int off = t * 2048 + sub * 512;
            const int m = t * 16 + sub * 4 + mo;
            const float4 ka = *(const float4*)(kp + off);
            const float4 kb = *(const float4*)(kp + off + 4);
            if (t < n10) {
                const float4 ta = *(const float4*)(t0p + off);
                const float4 tb = *(const float4*)(t0p + off + 4);
                float pp = q00.x*(ka.x+ta.x) + q00.y*(ka.y+ta.y)
                         + q00.z*(ka.z+ta.z) + q00.w*(ka.w+ta.w)
                         + q01.x*(kb.x+tb.x) + q01.y*(kb.y+tb.y)
                         + q01.z*(kb.z+tb.z) + q01.w*(kb.w+tb.w);
                pp += __shfl_xor(pp, 1);
                pp += __shfl_xor(pp, 2);
                if ((lane & 3) == 0) sc[0][hq][m] = (m <= l0) ? pp : kNEG;
            }
            if (t < n11) {
                const float4 ta = *(const float4*)(t1p + off);
                const float4 tb = *(const float4*)(t1p + off + 4);
                float pp = q10.x*(ka.x+ta.x) + q10.y*(ka.y+ta.y)
                         + q10.z*(ka.z+ta.z) + q10.w*(ka.w+ta.w)
                         + q11.x*(kb.x+tb.x) + q11.y*(kb.y+tb.y)
                         + q11.z*(kb.z+tb.z) + q11.w*(kb.w+tb.w);
                pp += __shfl_xor(pp, 1);
                pp += __shfl_xor(pp, 2);
                if ((lane & 3) == 0) sc[1][hq][m] = (m <= l1) ? pp : kNEG;
            }
        }
    }
    __syncthreads();

    // ---- softmax: wave w = head w, both l's; guarded reads, full writeback
    if (!mk0) {
        float v0 = (lane       <= l0) ? sc[0][w][lane]       : kNEG;
        float v1 = (lane + 64  <= l0) ? sc[0][w][lane + 64]  : kNEG;
        float v2 = (lane + 128 <= l0) ? sc[0][w][lane + 128] : kNEG;
        float v3 = (lane + 192 <= l0) ? sc[0][w][lane + 192] : kNEG;
        float mx = fmaxf(fmaxf(v0, v1), fmaxf(v2, v3));
        #pragma unroll
        for (int d = 1; d < 64; d <<= 1) mx = fmaxf(mx, __shfl_xor(mx, d));
        v0 = expf(v0 - mx); v1 = expf(v1 - mx);
        v2 = expf(v2 - mx); v3 = expf(v3 - mx);
        float sum = v0 + v1 + v2 + v3;
        #pragma unroll
        for (int d = 1; d < 64; d <<= 1) sum += __shfl_xor(sum, d);
        const float inv = 1.0f / sum;
        sc[0][w][lane]       = v0 * inv;    // m>l0 -> exact 0
        sc[0][w][lane + 64]  = v1 * inv;
        sc[0][w][lane + 128] = v2 * inv;
        sc[0][w][lane + 192] = v3 * inv;
    }
    if (!mk1) {
        float v0 = (lane       <= l1) ? sc[1][w][lane]       : kNEG;
        float v1 = (lane + 64  <= l1) ? sc[1][w][lane + 64]  : kNEG;
        float v2 = (lane + 128 <= l1) ? sc[1][w][lane + 128] : kNEG;
        float v3 = (lane + 192 <= l1) ? sc[1][w][lane + 192] : kNEG;
        float mx = fmaxf(fmaxf(v0, v1), fmaxf(v2, v3));
        #pragma unroll
        for (int d = 1; d < 64; d <<= 1) mx = fmaxf(mx, __shfl_xor(mx, d));
        v0 = expf(v0 - mx); v1 = expf(v1 - mx);
        v2 = expf(v2 - mx); v3 = expf(v3 - mx);
        float sum = v0 + v1 + v2 + v3;
        #pragma unroll
        for (int d = 1; d < 64; d <<= 1) sum += __shfl_xor(sum, d);
        const float inv = 1.0f / sum;
        sc[1][w][lane]       = v0 * inv;
        sc[1][w][lane + 64]  = v1 * inv;
        sc[1][w][lane + 128] = v2 * inv;
        sc[1][w][lane + 192] = v3 * inv;
    }
    __syncthreads();

    // ---- phase 2: output partials (same tile split, full-row V/tV reads) --
    float4 a00 = {0,0,0,0}, a01 = {0,0,0,0};
    float4 a10 = {0,0,0,0}, a11 = {0,0,0,0};
    for (int k = 0; k < 4; ++k) {
        const int t = w + k * 4;
        if (t >= NT2) break;
        #pragma unroll
        for (int sub = 0; sub < 4; ++sub) {
            const int off = t * 2048 + sub * 512;
            const int m = t * 16 + sub * 4 + mo;
            const float4 va = *(const float4*)(vp + off);
            const float4 vb = *(const float4*)(vp + off + 4);
            if (t < n20) {
                const float aw = mk0 ? kUni : sc[0][hq][m];
                const float4 ta = *(const float4*)(u0p + off);
                const float4 tb = *(const float4*)(u0p + off + 4);
                a00.x += aw*(va.x+ta.x); a00.y += aw*(va.y+ta.y);
                a00.z += aw*(va.z+ta.z); a00.w += aw*(va.w+ta.w);
                a01.x += aw*(vb.x+tb.x); a01.y += aw*(vb.y+tb.y);
                a01.z += aw*(vb.z+tb.z); a01.w += aw*(vb.w+tb.w);
            }
            if (t < n21) {
                const float aw = mk1 ? kUni : sc[1][hq][m];
                const float4 ta = *(const float4*)(u1p + off);
                const float4 tb = *(const float4*)(u1p + off + 4);
                a10.x += aw*(va.x+ta.x); a10.y += aw*(va.y+ta.y);
                a10.z += aw*(va.z+ta.z); a10.w += aw*(va.w+ta.w);
                a11.x += aw*(vb.x+tb.x); a11.y += aw*(vb.y+tb.y);
                a11.z += aw*(vb.z+tb.z); a11.w += aw*(vb.w+tb.w);
            }
        }
    }
    // reduce over mo (lane bits 4,5), then stash per-wave partials
    #pragma unroll
    for (int d = 16; d < 64; d <<= 1) {
        a00.x += __shfl_xor(a00.x, d); a00.y += __shfl_xor(a00.y, d);
        a00.z += __shfl_xor(a00.z, d); a00.w += __shfl_xor(a00.w, d);
        a01.x += __shfl_xor(a01.x, d); a01.y += __shfl_xor(a01.y, d);
        a01.z += __shfl_xor(a01.z, d); a01.w += __shfl_xor(a01.w, d);
        a10.x += __shfl_xor(a10.x, d); a10.y += __shfl_xor(a10.y, d);
        a10.z += __shfl_xor(a10.z, d); a10.w += __shfl_xor(a10.w, d);
        a11.x += __shfl_xor(a11.x, d); a11.y += __shfl_xor(a11.y, d);
        a11.z += __shfl_xor(a11.z, d); a11.w += __shfl_xor(a11.w, d);
    }
    if (mo == 0) {
        *(float4*)&op[w][0][cg * 8]     = a00;
        *(float4*)&op[w][0][cg * 8 + 4] = a01;
        *(float4*)&op[w][1][cg * 8]     = a10;
        *(float4*)&op[w][1][cg * 8 + 4] = a11;
    }
    __syncthreads();

    // ---- final cross-wave reduce + store (coalesced) ----
    {
        const int li = tid >> 7, ch = tid & 127;
        const float s = op[0][li][ch] + op[1][li][ch]
                      + op[2][li][ch] + op[3][li][ch];
        out[(li ? row1 : row0) + ch] = s;
    }
}

// ---------------------------------------------------------------------------
extern "C" void kernel_launch(void* const* d_in, const int* in_sizes, int n_in,
                              void* d_out, int out_size, void* d_ws, size_t ws_size,
                              hipStream_t stream) {
    const float* queries = (const float*)d_in[0];
    const float* keys    = (const float*)d_in[1];
    const float* tK      = (const float*)d_in[2];
    const float* tV      = (const float*)d_in[3];
    const float* absK    = (const float*)d_in[4];
    const float* absV    = (const float*)d_in[5];
    const float* Wq      = (const float*)d_in[6];
    const float* bq      = (const float*)d_in[7];
    const float* Wk      = (const float*)d_in[8];
    const float* bk      = (const float*)d_in[9];
    const float* Wv      = (const float*)d_in[10];
    const float* bv      = (const float*)d_in[11];
    const unsigned char* tmask_raw = (const unsigned char*)d_in[12];
    // d_in[13] (attn_mask) is deterministic triu(k=1) -> handled in-kernel.

    float* outp = (float*)d_out;

    const int rows = Bdim * Lq;                    // 2048
    float* Qb = (float*)d_ws;                      // 1 MB
    float* Kb = Qb + (size_t)rows * Hd;            // 1 MB
    float* Vb = Kb + (size_t)rows * Hd;            // 1 MB
    int* tmask = (int*)(Vb + (size_t)rows * Hd);   // 8 KB
    float* Wt = (float*)(tmask + rows);            // 192 KB (3 transposed W)

    prep_kernel<<<13, 256, 0, stream>>>(Wq, Wk, Wv, tmask_raw, Wt, tmask);
    proj_kernel<<<rows / 8, 512, 0, stream>>>(queries, keys, absK, absV, Wt,
                                              bq, bk, bv, Qb, Kb, Vb);
    attn_kernel<<<1024, 256, 0, stream>>>(Qb, Kb, Vb, tK, tV, tmask, outp);
}